// Round 1
// baseline (885.531 us; speedup 1.0000x reference)
//
#include <hip/hip_runtime.h>
#include <stdint.h>

typedef _Float16 f16;
typedef __attribute__((ext_vector_type(4))) _Float16 f16x4;
typedef __attribute__((ext_vector_type(8))) _Float16 f16x8;
typedef __attribute__((ext_vector_type(4))) float f32x4;

#define EPSF 1e-6f

using as1_cvoid = const __attribute__((address_space(1))) void;
using as3_void  = __attribute__((address_space(3))) void;

__device__ __forceinline__ float blockReduceSum256(float v) {
#pragma unroll
  for (int o = 32; o > 0; o >>= 1) v += __shfl_down(v, o);
  __shared__ float red[4];
  int lane = threadIdx.x & 63, wid = threadIdx.x >> 6;
  if (lane == 0) red[wid] = v;
  __syncthreads();
  return red[0] + red[1] + red[2] + red[3];
}

__global__ __launch_bounds__(256) void cvt_f32_f16(const float* __restrict__ src,
                                                   f16* __restrict__ dst, int n) {
  int i = (blockIdx.x * 256 + threadIdx.x) * 4;
  if (i >= n) return;
  float4 v = *(const float4*)(src + i);
  f16x4 o = {(f16)v.x, (f16)v.y, (f16)v.z, (f16)v.w};
  *(f16x4*)(dst + i) = o;
}

// One block per row of 1024; Y = rmsnorm(X)*w in fp16
__global__ __launch_bounds__(256) void rmsnorm_rows(const float* __restrict__ X,
                                                    const float* __restrict__ w,
                                                    f16* __restrict__ Y) {
  const size_t row = blockIdx.x;
  const int t = threadIdx.x;
  float4 v = ((const float4*)(X + row * 1024))[t];
  float tot = blockReduceSum256(v.x * v.x + v.y * v.y + v.z * v.z + v.w * v.w);
  float s = rsqrtf(tot * (1.0f / 1024.0f) + EPSF);
  float4 wv = ((const float4*)w)[t];
  f16x4 o = {(f16)(v.x * s * wv.x), (f16)(v.y * s * wv.y),
             (f16)(v.z * s * wv.z), (f16)(v.w * s * wv.w)};
  *(f16x4*)(Y + row * 1024 + t * 4) = o;
}

// slots -> sn = rmsnorm(slots)*w (f16) and sraw = slots (f16)
__global__ __launch_bounds__(256) void slots_prep(const float* __restrict__ S,
                                                  const float* __restrict__ w,
                                                  f16* __restrict__ sn,
                                                  f16* __restrict__ sraw) {
  const size_t row = blockIdx.x;
  const int t = threadIdx.x;
  float4 v = ((const float4*)(S + row * 1024))[t];
  float tot = blockReduceSum256(v.x * v.x + v.y * v.y + v.z * v.z + v.w * v.w);
  float s = rsqrtf(tot * (1.0f / 1024.0f) + EPSF);
  float4 wv = ((const float4*)w)[t];
  f16x4 a = {(f16)(v.x * s * wv.x), (f16)(v.y * s * wv.y),
             (f16)(v.z * s * wv.z), (f16)(v.w * s * wv.w)};
  f16x4 b = {(f16)v.x, (f16)v.y, (f16)v.z, (f16)v.w};
  *(f16x4*)(sn + row * 1024 + t * 4) = a;
  *(f16x4*)(sraw + row * 1024 + t * 4) = b;
}

// C = alpha * A(MxK) @ B(NxK)^T ; A,B f16 row-major (K contiguous).
// STORE: 0 = fp32 out ; 1 = f16 out (optional per-row scale alpha/(rowscale+eps)) ;
//        2 = f16 out transposed per batch-of-4096-rows: out[b][n][m] (vT special)
template <int BM, int BN, int WM, int WN, int STORE>
__global__ __launch_bounds__(256) void gemm_bt(
    const f16* __restrict__ A, const f16* __restrict__ B, void* __restrict__ Cout,
    const float* __restrict__ rowscale, int lda, int ldb, int ldc, int K,
    long sA, long sB, long sC, int rsStride, float alpha) {
  constexpr int AM = WM / 16, AN = WN / 16;
  constexpr int NWN = BN / WN;
  constexpr int AI = BM / 64, BI = BN / 64;
  __shared__ f16 Al[BM * 32];
  __shared__ f16 Bl[BN * 32];
  const int tid = threadIdx.x;
  const int wave = tid >> 6, lane = tid & 63;
  const int wm = wave / NWN, wn = wave % NWN;
  const int z = blockIdx.z;
  const f16* Ab = A + (size_t)z * sA;
  const f16* Bb = B + (size_t)z * sB;
  const int m0 = blockIdx.y * BM, n0 = blockIdx.x * BN;
  const int cr = lane & 15, kseg = lane >> 4;

  f32x4 acc[AM][AN];
  f32x4 vzero = {0.f, 0.f, 0.f, 0.f};
#pragma unroll
  for (int i = 0; i < AM; ++i) {
#pragma unroll
    for (int j = 0; j < AN; ++j) acc[i][j] = vzero;
  }

  const int nK = K >> 5;
  for (int kt = 0; kt < nK; ++kt) {
    const int k0 = kt << 5;
#pragma unroll
    for (int it = 0; it < AI; ++it) {
      const int chunk = it * 4 + wave;
      const int off = chunk * 1024 + lane * 16;
      const int r = off >> 6, cb = off & 63;
      const char* src = (const char*)(Ab + (size_t)(m0 + r) * lda + k0) + cb;
      __builtin_amdgcn_global_load_lds((as1_cvoid*)src,
                                       (as3_void*)((char*)Al + chunk * 1024), 16, 0, 0);
    }
#pragma unroll
    for (int it = 0; it < BI; ++it) {
      const int chunk = it * 4 + wave;
      const int off = chunk * 1024 + lane * 16;
      const int r = off >> 6, cb = off & 63;
      const char* src = (const char*)(Bb + (size_t)(n0 + r) * ldb + k0) + cb;
      __builtin_amdgcn_global_load_lds((as1_cvoid*)src,
                                       (as3_void*)((char*)Bl + chunk * 1024), 16, 0, 0);
    }
    __syncthreads();
    f16x8 af[AM], bfv[AN];
#pragma unroll
    for (int i = 0; i < AM; ++i)
      af[i] = *(const f16x8*)&Al[(wm * WM + i * 16 + cr) * 32 + kseg * 8];
#pragma unroll
    for (int j = 0; j < AN; ++j)
      bfv[j] = *(const f16x8*)&Bl[(wn * WN + j * 16 + cr) * 32 + kseg * 8];
#pragma unroll
    for (int i = 0; i < AM; ++i) {
#pragma unroll
      for (int j = 0; j < AN; ++j)
        acc[i][j] = __builtin_amdgcn_mfma_f32_16x16x32_f16(af[i], bfv[j], acc[i][j], 0, 0, 0);
    }
    __syncthreads();
  }

  const int cq4 = (lane >> 4) * 4;
  if constexpr (STORE == 2) {
    f16* O = (f16*)Cout;
#pragma unroll
    for (int i = 0; i < AM; ++i) {
      const int gm = m0 + wm * WM + i * 16 + cq4;
      const int b = gm >> 12, ml = gm & 4095;
#pragma unroll
      for (int j = 0; j < AN; ++j) {
        const int gn = n0 + wn * WN + j * 16 + cr;
        f16x4 o = {(f16)(acc[i][j][0] * alpha), (f16)(acc[i][j][1] * alpha),
                   (f16)(acc[i][j][2] * alpha), (f16)(acc[i][j][3] * alpha)};
        *(f16x4*)(O + ((size_t)b * 1024 + gn) * 4096 + ml) = o;
      }
    }
  } else if constexpr (STORE == 0) {
    float* O = (float*)Cout + (size_t)z * sC;
#pragma unroll
    for (int i = 0; i < AM; ++i) {
      const int rb = m0 + wm * WM + i * 16 + cq4;
#pragma unroll
      for (int j = 0; j < AN; ++j) {
        const int gn = n0 + wn * WN + j * 16 + cr;
#pragma unroll
        for (int r = 0; r < 4; ++r) O[(size_t)(rb + r) * ldc + gn] = acc[i][j][r] * alpha;
      }
    }
  } else {
    f16* O = (f16*)Cout + (size_t)z * sC;
#pragma unroll
    for (int i = 0; i < AM; ++i) {
      const int rb = m0 + wm * WM + i * 16 + cq4;
      float rs[4];
#pragma unroll
      for (int r = 0; r < 4; ++r)
        rs[r] = rowscale ? (alpha / (rowscale[z * rsStride + rb + r] + EPSF)) : alpha;
#pragma unroll
      for (int j = 0; j < AN; ++j) {
        const int gn = n0 + wn * WN + j * 16 + cr;
#pragma unroll
        for (int r = 0; r < 4; ++r)
          O[(size_t)(rb + r) * ldc + gn] = (f16)(acc[i][j][r] * rs[r]);
      }
    }
  }
}

// softmax over the 64 slots per (b, m) column; scores (8,64,4096) fp32 -> attn f16
__global__ __launch_bounds__(256) void softmax_k64(const float* __restrict__ S,
                                                   f16* __restrict__ A) {
  const int b = blockIdx.x >> 4;
  const int m = ((blockIdx.x & 15) << 8) | threadIdx.x;
  const float* s = S + (size_t)b * 262144 + m;
  f16* a = A + (size_t)b * 262144 + m;
  float v[64];
  float mx = -1e30f;
#pragma unroll
  for (int k = 0; k < 64; ++k) {
    v[k] = s[(size_t)k * 4096];
    mx = fmaxf(mx, v[k]);
  }
  float sum = 0.f;
#pragma unroll
  for (int k = 0; k < 64; ++k) {
    v[k] = __expf(v[k] - mx);
    sum += v[k];
  }
  float inv = 1.0f / sum;
#pragma unroll
  for (int k = 0; k < 64; ++k) a[(size_t)k * 4096] = (f16)(v[k] * inv);
}

// one block per (b,k): rowsum over m of attn
__global__ __launch_bounds__(256) void rowsum_k(const f16* __restrict__ A,
                                                float* __restrict__ rs) {
  const int bk = blockIdx.x;
  const f16* a = A + (size_t)bk * 4096;
  const int t = threadIdx.x;
  f16x8 u0 = *(const f16x8*)(a + t * 16);
  f16x8 u1 = *(const f16x8*)(a + t * 16 + 8);
  float s = 0.f;
#pragma unroll
  for (int i = 0; i < 8; ++i) s += (float)u0[i] + (float)u1[i];
  float tot = blockReduceSum256(s);
  if (threadIdx.x == 0) rs[bk] = tot;
}

// GRU gates, elementwise over (512,1024); h updated in place (d_out)
__global__ __launch_bounds__(256) void gru_gates(const float* __restrict__ gx,
                                                 const float* __restrict__ gh,
                                                 const float* __restrict__ bih,
                                                 const float* __restrict__ bhh,
                                                 float* __restrict__ h) {
  const int idx = blockIdx.x * 256 + threadIdx.x;
  const int row = idx >> 10, col = idx & 1023;
  const float* gxr = gx + (size_t)row * 3072;
  const float* ghr = gh + (size_t)row * 3072;
  float xr = gxr[col] + bih[col];
  float xz = gxr[col + 1024] + bih[col + 1024];
  float xn = gxr[col + 2048] + bih[col + 2048];
  float hr = ghr[col] + bhh[col];
  float hz = ghr[col + 1024] + bhh[col + 1024];
  float hn = ghr[col + 2048] + bhh[col + 2048];
  float r = 1.f / (1.f + __expf(-(xr + hr)));
  float zz = 1.f / (1.f + __expf(-(xz + hz)));
  float n = tanhf(xn + r * hn);
  float hv = h[idx];
  h[idx] = (1.f - zz) * n + zz * hv;
}

extern "C" void kernel_launch(void* const* d_in, const int* in_sizes, int n_in,
                              void* d_out, int out_size, void* d_ws, size_t ws_size,
                              hipStream_t stream) {
  (void)in_sizes; (void)n_in; (void)out_size; (void)ws_size;
  const float* slots = (const float*)d_in[0];
  const float* P = (const float*)d_in[1];
  const float* Wq = (const float*)d_in[2];
  const float* Wk = (const float*)d_in[3];
  const float* Wv = (const float*)d_in[4];
  const float* wih = (const float*)d_in[5];
  const float* whh = (const float*)d_in[6];
  const float* bih = (const float*)d_in[7];
  const float* bhh = (const float*)d_in[8];
  const float* snw = (const float*)d_in[9];
  const float* inw = (const float*)d_in[10];
  float* out = (float*)d_out;
  char* ws = (char*)d_ws;

  // workspace layout (bytes)
  f16* kproj = (f16*)(ws + 0);           // 32768x1024 f16 = 64 MB
  f16* vT    = (f16*)(ws + 67108864);    // 8 x 1024 x 4096 f16 = 64 MB
  char* rgn  = ws + 134217728;           // 64 MB region: Pn, then loop scratch (aliased)
  f16* Pn    = (f16*)rgn;                // 32768x1024 f16
  float* scores = (float*)rgn;           // 8x64x4096 fp32 (8 MB)  [aliases Pn, used after]
  f16* attn  = (f16*)(rgn + 8388608);    // 8x64x4096 f16 (4 MB)
  f16* qb    = (f16*)(rgn + 12582912);   // 512x1024 f16
  f16* sn    = (f16*)(rgn + 13631488);   // 512x1024 f16
  f16* sbf   = (f16*)(rgn + 14680064);   // 512x1024 f16
  f16* upd   = (f16*)(rgn + 15728640);   // 512x1024 f16
  float* gxb = (float*)(rgn + 16777216); // 512x3072 fp32 (6 MB)
  float* ghb = (float*)(rgn + 23068672); // 512x3072 fp32 (6 MB)
  char* wr = ws + 201326592;
  f16* Wqh  = (f16*)(wr + 0);
  f16* Wkh  = (f16*)(wr + 2097152);
  f16* Wvh  = (f16*)(wr + 4194304);
  f16* wihh = (f16*)(wr + 6291456);
  f16* whhh = (f16*)(wr + 12582912);
  float* rowsum = (float*)(wr + 18874368); // 512 fp32

  // weights -> f16
  cvt_f32_f16<<<1024, 256, 0, stream>>>(Wq, Wqh, 1048576);
  cvt_f32_f16<<<1024, 256, 0, stream>>>(Wk, Wkh, 1048576);
  cvt_f32_f16<<<1024, 256, 0, stream>>>(Wv, Wvh, 1048576);
  cvt_f32_f16<<<3072, 256, 0, stream>>>(wih, wihh, 3145728);
  cvt_f32_f16<<<3072, 256, 0, stream>>>(whh, whhh, 3145728);

  // Pn = rmsnorm(P) * input_norm_w
  rmsnorm_rows<<<32768, 256, 0, stream>>>(P, inw, Pn);

  // k_proj = Pn @ Wk^T  (f16, row-major)
  gemm_bt<128, 128, 64, 64, 1><<<dim3(8, 256, 1), 256, 0, stream>>>(
      Pn, Wkh, kproj, nullptr, 1024, 1024, 1024, 1024, 0, 0, 0, 0, 1.0f);
  // vT[b][d][m] = (Pn @ Wv^T)^T per batch  (f16)
  gemm_bt<128, 128, 64, 64, 2><<<dim3(8, 256, 1), 256, 0, stream>>>(
      Pn, Wvh, vT, nullptr, 1024, 1024, 0, 1024, 0, 0, 0, 0, 1.0f);

  // working slots live in d_out (fp32)
  hipMemcpyAsync(out, slots, 2097152, hipMemcpyDeviceToDevice, stream);

  for (int it = 0; it < 3; ++it) {
    slots_prep<<<512, 256, 0, stream>>>(out, snw, sn, sbf);
    // q = sn @ Wq^T
    gemm_bt<64, 128, 32, 64, 1><<<dim3(8, 8, 1), 256, 0, stream>>>(
        sn, Wqh, qb, nullptr, 1024, 1024, 1024, 1024, 0, 0, 0, 0, 1.0f);
    // scores[b] = SCALE * q_b @ k_b^T   (fp32)
    gemm_bt<64, 128, 32, 64, 0><<<dim3(32, 1, 8), 256, 0, stream>>>(
        qb, kproj, scores, nullptr, 1024, 1024, 4096, 1024,
        65536, 4194304, 262144, 0, 0.03125f);
    softmax_k64<<<128, 256, 0, stream>>>(scores, attn);
    rowsum_k<<<512, 256, 0, stream>>>(attn, rowsum);
    // upd[b] = (attn_b / (rowsum+eps)) @ v_b   via vT, contraction over m
    gemm_bt<64, 64, 32, 32, 1><<<dim3(16, 1, 8), 256, 0, stream>>>(
        attn, vT, upd, rowsum, 4096, 4096, 1024, 4096,
        262144, 4194304, 65536, 64, 1.0f);
    // gx = upd @ wih^T ; gh = slots @ whh^T  (fp32 out)
    gemm_bt<64, 128, 32, 64, 0><<<dim3(24, 8, 1), 256, 0, stream>>>(
        upd, wihh, gxb, nullptr, 1024, 1024, 3072, 1024, 0, 0, 0, 0, 1.0f);
    gemm_bt<64, 128, 32, 64, 0><<<dim3(24, 8, 1), 256, 0, stream>>>(
        sbf, whhh, ghb, nullptr, 1024, 1024, 3072, 1024, 0, 0, 0, 0, 1.0f);
    gru_gates<<<2048, 256, 0, stream>>>(gxb, ghb, bih, bhh, out);
  }
}

// Round 5
// 689.210 us; speedup vs baseline: 1.2849x; 1.2849x over previous
//
#include <hip/hip_runtime.h>
#include <stdint.h>

typedef _Float16 f16;
typedef __attribute__((ext_vector_type(4))) _Float16 f16x4;
typedef __attribute__((ext_vector_type(8))) _Float16 f16x8;
typedef __attribute__((ext_vector_type(4))) float f32x4;

#define EPSF 1e-6f

using as1_cvoid = const __attribute__((address_space(1))) void;
using as3_void  = __attribute__((address_space(3))) void;

__device__ __forceinline__ float blockReduceSum256(float v) {
#pragma unroll
  for (int o = 32; o > 0; o >>= 1) v += __shfl_down(v, o);
  __shared__ float red[4];
  int lane = threadIdx.x & 63, wid = threadIdx.x >> 6;
  if (lane == 0) red[wid] = v;
  __syncthreads();
  return red[0] + red[1] + red[2] + red[3];
}

__global__ __launch_bounds__(256) void cvt_f32_f16(const float* __restrict__ src,
                                                   f16* __restrict__ dst, int n) {
  int i = (blockIdx.x * 256 + threadIdx.x) * 4;
  if (i >= n) return;
  float4 v = *(const float4*)(src + i);
  f16x4 o = {(f16)v.x, (f16)v.y, (f16)v.z, (f16)v.w};
  *(f16x4*)(dst + i) = o;
}

// One block per row of 1024; Y = rmsnorm(X)*w in fp16
__global__ __launch_bounds__(256) void rmsnorm_rows(const float* __restrict__ X,
                                                    const float* __restrict__ w,
                                                    f16* __restrict__ Y) {
  const size_t row = blockIdx.x;
  const int t = threadIdx.x;
  float4 v = ((const float4*)(X + row * 1024))[t];
  float tot = blockReduceSum256(v.x * v.x + v.y * v.y + v.z * v.z + v.w * v.w);
  float s = rsqrtf(tot * (1.0f / 1024.0f) + EPSF);
  float4 wv = ((const float4*)w)[t];
  f16x4 o = {(f16)(v.x * s * wv.x), (f16)(v.y * s * wv.y),
             (f16)(v.z * s * wv.z), (f16)(v.w * s * wv.w)};
  *(f16x4*)(Y + row * 1024 + t * 4) = o;
}

// slots -> sn = rmsnorm(slots)*w (f16), sraw = slots (f16); zero rowsum
__global__ __launch_bounds__(256) void slots_prep(const float* __restrict__ S,
                                                  const float* __restrict__ w,
                                                  f16* __restrict__ sn,
                                                  f16* __restrict__ sraw,
                                                  float* __restrict__ rowsum) {
  const size_t row = blockIdx.x;
  const int t = threadIdx.x;
  if (t == 0) rowsum[row] = 0.f;
  float4 v = ((const float4*)(S + row * 1024))[t];
  float tot = blockReduceSum256(v.x * v.x + v.y * v.y + v.z * v.z + v.w * v.w);
  float s = rsqrtf(tot * (1.0f / 1024.0f) + EPSF);
  float4 wv = ((const float4*)w)[t];
  f16x4 a = {(f16)(v.x * s * wv.x), (f16)(v.y * s * wv.y),
             (f16)(v.z * s * wv.z), (f16)(v.w * s * wv.w)};
  f16x4 b = {(f16)v.x, (f16)v.y, (f16)v.z, (f16)v.w};
  *(f16x4*)(sn + row * 1024 + t * 4) = a;
  *(f16x4*)(sraw + row * 1024 + t * 4) = b;
}

// Fused K+V projection: kproj = Pn@Wk^T (row-major f16), vT[b][d][m] = (Pn@Wv^T)^T.
// 8 waves: waves 0-3 compute K-output, waves 4-7 V-output, shared A staging.
// XCD-aware bijective swizzle: blocks sharing an A-panel land on one XCD.
__global__ __launch_bounds__(512) void gemm_kv(
    const f16* __restrict__ Pn, const f16* __restrict__ Wk, const f16* __restrict__ Wv,
    f16* __restrict__ kproj, f16* __restrict__ vT) {
  __shared__ f16 Al[128 * 32];
  __shared__ f16 Bkv[2][128 * 32];
  const int tid = threadIdx.x;
  const int wave = tid >> 6, lane = tid & 63;
  const int id = blockIdx.x;
  const int xcd = id & 7, slot = id >> 3;
  const int nx = slot & 7;               // n-tile 0..7
  const int my = xcd * 32 + (slot >> 3); // m-tile 0..255
  const int m0 = my * 128, n0 = nx * 128;
  const int wsel = wave >> 2;            // 0 = K-out, 1 = V-out
  const int w4 = wave & 3;
  const int wm = w4 >> 1, wn = w4 & 1;   // 2x2 waves over 128x128
  const int cr = lane & 15, kseg = lane >> 4;

  f32x4 acc[4][4];
  f32x4 vzero = {0.f, 0.f, 0.f, 0.f};
#pragma unroll
  for (int i = 0; i < 4; ++i)
#pragma unroll
    for (int j = 0; j < 4; ++j) acc[i][j] = vzero;

  const int off = wave * 1024 + lane * 16;
  const int sr = off >> 6, scb = off & 63;
  for (int kt = 0; kt < 32; ++kt) {
    const int k0 = kt << 5;
    {
      const char* src = (const char*)(Pn + (size_t)(m0 + sr) * 1024 + k0) + scb;
      __builtin_amdgcn_global_load_lds((as1_cvoid*)src,
                                       (as3_void*)((char*)Al + wave * 1024), 16, 0, 0);
    }
    {
      const char* src = (const char*)(Wk + (size_t)(n0 + sr) * 1024 + k0) + scb;
      __builtin_amdgcn_global_load_lds((as1_cvoid*)src,
                                       (as3_void*)((char*)&Bkv[0][0] + wave * 1024), 16, 0, 0);
    }
    {
      const char* src = (const char*)(Wv + (size_t)(n0 + sr) * 1024 + k0) + scb;
      __builtin_amdgcn_global_load_lds((as1_cvoid*)src,
                                       (as3_void*)((char*)&Bkv[1][0] + wave * 1024), 16, 0, 0);
    }
    __syncthreads();
    f16x8 af[4], bf[4];
#pragma unroll
    for (int i = 0; i < 4; ++i)
      af[i] = *(const f16x8*)&Al[(wm * 64 + i * 16 + cr) * 32 + kseg * 8];
#pragma unroll
    for (int j = 0; j < 4; ++j)
      bf[j] = *(const f16x8*)&Bkv[wsel][(wn * 64 + j * 16 + cr) * 32 + kseg * 8];
#pragma unroll
    for (int i = 0; i < 4; ++i)
#pragma unroll
      for (int j = 0; j < 4; ++j)
        acc[i][j] = __builtin_amdgcn_mfma_f32_16x16x32_f16(af[i], bf[j], acc[i][j], 0, 0, 0);
    __syncthreads();
  }

  const int cq4 = kseg * 4;
  if (wsel == 0) {
#pragma unroll
    for (int i = 0; i < 4; ++i) {
      const int rb = m0 + wm * 64 + i * 16 + cq4;
#pragma unroll
      for (int j = 0; j < 4; ++j) {
        const int gn = n0 + wn * 64 + j * 16 + cr;
#pragma unroll
        for (int r = 0; r < 4; ++r)
          kproj[(size_t)(rb + r) * 1024 + gn] = (f16)acc[i][j][r];
      }
    }
  } else {
#pragma unroll
    for (int i = 0; i < 4; ++i) {
      const int gm = m0 + wm * 64 + i * 16 + cq4;
      const int b = gm >> 12, ml = gm & 4095;
#pragma unroll
      for (int j = 0; j < 4; ++j) {
        const int gn = n0 + wn * 64 + j * 16 + cr;
        f16x4 o = {(f16)acc[i][j][0], (f16)acc[i][j][1],
                   (f16)acc[i][j][2], (f16)acc[i][j][3]};
        *(f16x4*)(vT + ((size_t)b * 1024 + gn) * 4096 + ml) = o;
      }
    }
  }
}

// C = alpha * A(MxK) @ B(NxK)^T ; f16 in. STORE: 0 = fp32 out, 1 = f16 out.
// SPLITK>0: blockIdx.y = K-chunk (width SPLITK), m0 = 0, out += y*sY.
template <int BM, int BN, int WM, int WN, int STORE, int SPLITK>
__global__ __launch_bounds__(256) void gemm_bt(
    const f16* __restrict__ A, const f16* __restrict__ B, void* __restrict__ Cout,
    int lda, int ldb, int ldc, int K, long sA, long sB, long sC, long sY, float alpha) {
  constexpr int AM = WM / 16, AN = WN / 16;
  constexpr int NWN = BN / WN;
  constexpr int AI = BM / 64, BI = BN / 64;
  __shared__ f16 Al[BM * 32];
  __shared__ f16 Bl[BN * 32];
  const int tid = threadIdx.x;
  const int wave = tid >> 6, lane = tid & 63;
  const int wm = wave / NWN, wn = wave % NWN;
  const int z = blockIdx.z;
  const f16* Ab = A + (size_t)z * sA;
  const f16* Bb = B + (size_t)z * sB;
  const int m0 = SPLITK ? 0 : blockIdx.y * BM;
  const int n0 = blockIdx.x * BN;
  const int kbase = SPLITK ? blockIdx.y * SPLITK : 0;
  const int cr = lane & 15, kseg = lane >> 4;

  f32x4 acc[AM][AN];
  f32x4 vzero = {0.f, 0.f, 0.f, 0.f};
#pragma unroll
  for (int i = 0; i < AM; ++i)
#pragma unroll
    for (int j = 0; j < AN; ++j) acc[i][j] = vzero;

  const int nK = SPLITK ? (SPLITK >> 5) : (K >> 5);
  for (int kt = 0; kt < nK; ++kt) {
    const int k0 = kbase + (kt << 5);
#pragma unroll
    for (int it = 0; it < AI; ++it) {
      const int chunk = it * 4 + wave;
      const int off = chunk * 1024 + lane * 16;
      const int r = off >> 6, cb = off & 63;
      const char* src = (const char*)(Ab + (size_t)(m0 + r) * lda + k0) + cb;
      __builtin_amdgcn_global_load_lds((as1_cvoid*)src,
                                       (as3_void*)((char*)Al + chunk * 1024), 16, 0, 0);
    }
#pragma unroll
    for (int it = 0; it < BI; ++it) {
      const int chunk = it * 4 + wave;
      const int off = chunk * 1024 + lane * 16;
      const int r = off >> 6, cb = off & 63;
      const char* src = (const char*)(Bb + (size_t)(n0 + r) * ldb + k0) + cb;
      __builtin_amdgcn_global_load_lds((as1_cvoid*)src,
                                       (as3_void*)((char*)Bl + chunk * 1024), 16, 0, 0);
    }
    __syncthreads();
    f16x8 af[AM], bfv[AN];
#pragma unroll
    for (int i = 0; i < AM; ++i)
      af[i] = *(const f16x8*)&Al[(wm * WM + i * 16 + cr) * 32 + kseg * 8];
#pragma unroll
    for (int j = 0; j < AN; ++j)
      bfv[j] = *(const f16x8*)&Bl[(wn * WN + j * 16 + cr) * 32 + kseg * 8];
#pragma unroll
    for (int i = 0; i < AM; ++i)
#pragma unroll
      for (int j = 0; j < AN; ++j)
        acc[i][j] = __builtin_amdgcn_mfma_f32_16x16x32_f16(af[i], bfv[j], acc[i][j], 0, 0, 0);
    __syncthreads();
  }

  const int cq4 = kseg * 4;
  if constexpr (STORE == 0) {
    float* O = (float*)Cout + (size_t)z * sC + (SPLITK ? (size_t)blockIdx.y * sY : 0);
#pragma unroll
    for (int i = 0; i < AM; ++i) {
      const int rb = m0 + wm * WM + i * 16 + cq4;
#pragma unroll
      for (int j = 0; j < AN; ++j) {
        const int gn = n0 + wn * WN + j * 16 + cr;
#pragma unroll
        for (int r = 0; r < 4; ++r) O[(size_t)(rb + r) * ldc + gn] = acc[i][j][r] * alpha;
      }
    }
  } else {
    f16* O = (f16*)Cout + (size_t)z * sC;
#pragma unroll
    for (int i = 0; i < AM; ++i) {
      const int rb = m0 + wm * WM + i * 16 + cq4;
#pragma unroll
      for (int j = 0; j < AN; ++j) {
        const int gn = n0 + wn * WN + j * 16 + cr;
#pragma unroll
        for (int r = 0; r < 4; ++r)
          O[(size_t)(rb + r) * ldc + gn] = (f16)(acc[i][j][r] * alpha);
      }
    }
  }
}

// Fused scores + softmax(over k=64) + rowsum atomics.
// grid (32 m-chunks, 8 b), 256 threads. attn[b][k][m] f16 out.
__global__ __launch_bounds__(256) void attn_fused(
    const f16* __restrict__ qb, const f16* __restrict__ kproj,
    f16* __restrict__ attn, float* __restrict__ rowsum) {
  constexpr float SCALE = 0.03125f;
  __shared__ f16 Ql[64 * 32];
  __shared__ f16 Kl[128 * 32];
  __shared__ float sc[64][132];
  __shared__ f16 at[64][136];  // 272B rows: 16B-aligned for f16x8 epilogue reads
  const int b = blockIdx.y, m0 = blockIdx.x * 128;
  const int tid = threadIdx.x;
  const int wave = tid >> 6, lane = tid & 63;
  const int cr = lane & 15, kseg = lane >> 4;

  f32x4 acc[8];
  f32x4 vzero = {0.f, 0.f, 0.f, 0.f};
#pragma unroll
  for (int j = 0; j < 8; ++j) acc[j] = vzero;

  for (int kt = 0; kt < 32; ++kt) {
    const int k0 = kt << 5;
    {
      const int off = wave * 1024 + lane * 16;
      const int r = off >> 6, cb = off & 63;
      const char* src = (const char*)(qb + (size_t)(b * 64 + r) * 1024 + k0) + cb;
      __builtin_amdgcn_global_load_lds((as1_cvoid*)src,
                                       (as3_void*)((char*)Ql + wave * 1024), 16, 0, 0);
    }
#pragma unroll
    for (int it = 0; it < 2; ++it) {
      const int chunk = it * 4 + wave;
      const int off = chunk * 1024 + lane * 16;
      const int r = off >> 6, cb = off & 63;
      const char* src = (const char*)(kproj + ((size_t)b * 4096 + m0 + r) * 1024 + k0) + cb;
      __builtin_amdgcn_global_load_lds((as1_cvoid*)src,
                                       (as3_void*)((char*)Kl + chunk * 1024), 16, 0, 0);
    }
    __syncthreads();
    f16x8 aq = *(const f16x8*)&Ql[(wave * 16 + cr) * 32 + kseg * 8];
#pragma unroll
    for (int j = 0; j < 8; ++j) {
      f16x8 bk = *(const f16x8*)&Kl[(j * 16 + cr) * 32 + kseg * 8];
      acc[j] = __builtin_amdgcn_mfma_f32_16x16x32_f16(aq, bk, acc[j], 0, 0, 0);
    }
    __syncthreads();
  }
#pragma unroll
  for (int j = 0; j < 8; ++j)
#pragma unroll
    for (int r = 0; r < 4; ++r)
      sc[wave * 16 + kseg * 4 + r][j * 16 + cr] = acc[j][r] * SCALE;
  __syncthreads();

  if (tid < 128) {
    const int m = tid;
    float v[64];
    float mx = -1e30f;
#pragma unroll
    for (int k = 0; k < 64; ++k) {
      v[k] = sc[k][m];
      mx = fmaxf(mx, v[k]);
    }
    float sum = 0.f;
#pragma unroll
    for (int k = 0; k < 64; ++k) {
      v[k] = __expf(v[k] - mx);
      sum += v[k];
    }
    float inv = 1.0f / sum;
#pragma unroll
    for (int k = 0; k < 64; ++k) at[k][m] = (f16)(v[k] * inv);
  }
  __syncthreads();

  const int k = tid >> 2, seg = tid & 3;
  float s = 0.f;
  f16x8 u[4];
#pragma unroll
  for (int c = 0; c < 4; ++c) {
    u[c] = *(const f16x8*)&at[k][seg * 32 + c * 8];
#pragma unroll
    for (int e = 0; e < 8; ++e) s += (float)u[c][e];
  }
  f16* dst = attn + ((size_t)b * 64 + k) * 4096 + m0 + seg * 32;
#pragma unroll
  for (int c = 0; c < 4; ++c) *(f16x8*)(dst + c * 8) = u[c];
  s += __shfl_down(s, 2);
  s += __shfl_down(s, 1);
  if (seg == 0) atomicAdd(&rowsum[b * 64 + k], s);
}

// sum 4 split-k partials, scale by 1/(rowsum+eps), cvt f16
__global__ __launch_bounds__(256) void upd_reduce(const float* __restrict__ part,
                                                  const float* __restrict__ rowsum,
                                                  f16* __restrict__ upd) {
  const int idx = blockIdx.x * 256 + threadIdx.x;
  const int f0 = idx * 4;
  const int row = f0 >> 10;
  float4 s = *(const float4*)(part + f0);
#pragma unroll
  for (int c = 1; c < 4; ++c) {
    float4 p = *(const float4*)(part + c * 524288 + f0);
    s.x += p.x; s.y += p.y; s.z += p.z; s.w += p.w;
  }
  const float scl = 1.0f / (rowsum[row] + EPSF);
  f16x4 o = {(f16)(s.x * scl), (f16)(s.y * scl), (f16)(s.z * scl), (f16)(s.w * scl)};
  *(f16x4*)(upd + f0) = o;
}

// GRU gates, elementwise over (512,1024); h updated in place (d_out)
__global__ __launch_bounds__(256) void gru_gates(const float* __restrict__ gx,
                                                 const float* __restrict__ gh,
                                                 const float* __restrict__ bih,
                                                 const float* __restrict__ bhh,
                                                 float* __restrict__ h) {
  const int idx = blockIdx.x * 256 + threadIdx.x;
  const int row = idx >> 10, col = idx & 1023;
  const float* gxr = gx + (size_t)row * 3072;
  const float* ghr = gh + (size_t)row * 3072;
  float xr = gxr[col] + bih[col];
  float xz = gxr[col + 1024] + bih[col + 1024];
  float xn = gxr[col + 2048] + bih[col + 2048];
  float hr = ghr[col] + bhh[col];
  float hz = ghr[col + 1024] + bhh[col + 1024];
  float hn = ghr[col + 2048] + bhh[col + 2048];
  float r = 1.f / (1.f + __expf(-(xr + hr)));
  float zz = 1.f / (1.f + __expf(-(xz + hz)));
  float n = tanhf(xn + r * hn);
  float hv = h[idx];
  h[idx] = (1.f - zz) * n + zz * hv;
}

extern "C" void kernel_launch(void* const* d_in, const int* in_sizes, int n_in,
                              void* d_out, int out_size, void* d_ws, size_t ws_size,
                              hipStream_t stream) {
  (void)in_sizes; (void)n_in; (void)out_size; (void)ws_size;
  const float* slots = (const float*)d_in[0];
  const float* P = (const float*)d_in[1];
  const float* Wq = (const float*)d_in[2];
  const float* Wk = (const float*)d_in[3];
  const float* Wv = (const float*)d_in[4];
  const float* wih = (const float*)d_in[5];
  const float* whh = (const float*)d_in[6];
  const float* bih = (const float*)d_in[7];
  const float* bhh = (const float*)d_in[8];
  const float* snw = (const float*)d_in[9];
  const float* inw = (const float*)d_in[10];
  float* out = (float*)d_out;
  char* ws = (char*)d_ws;

  // workspace layout (bytes)
  f16* kproj = (f16*)(ws + 0);           // 64 MB
  f16* vT    = (f16*)(ws + 67108864);    // 64 MB
  char* rgn  = ws + 134217728;           // 64 MB region: Pn, then loop scratch (aliased)
  f16* Pn    = (f16*)rgn;                // 32768x1024 f16
  f16* attn  = (f16*)(rgn + 0);          // 8x64x4096 f16 (4 MB) [aliases Pn; Pn dead]
  float* part = (float*)(rgn + 4194304); // 4x8x64x1024 fp32 (8 MB)
  f16* qb    = (f16*)(rgn + 12582912);   // 512x1024 f16
  f16* sn    = (f16*)(rgn + 13631488);
  f16* sbf   = (f16*)(rgn + 14680064);
  f16* upd   = (f16*)(rgn + 15728640);
  float* gxb = (float*)(rgn + 16777216); // 512x3072 fp32 (6 MB)
  float* ghb = (float*)(rgn + 23068672); // 512x3072 fp32 (6 MB)
  char* wr = ws + 201326592;
  f16* Wqh  = (f16*)(wr + 0);
  f16* Wkh  = (f16*)(wr + 2097152);
  f16* Wvh  = (f16*)(wr + 4194304);
  f16* wihh = (f16*)(wr + 6291456);
  f16* whhh = (f16*)(wr + 12582912);
  float* rowsum = (float*)(wr + 18874368); // 512 fp32

  // weights -> f16
  cvt_f32_f16<<<1024, 256, 0, stream>>>(Wq, Wqh, 1048576);
  cvt_f32_f16<<<1024, 256, 0, stream>>>(Wk, Wkh, 1048576);
  cvt_f32_f16<<<1024, 256, 0, stream>>>(Wv, Wvh, 1048576);
  cvt_f32_f16<<<3072, 256, 0, stream>>>(wih, wihh, 3145728);
  cvt_f32_f16<<<3072, 256, 0, stream>>>(whh, whhh, 3145728);

  // Pn = rmsnorm(P) * input_norm_w  -- note Pn aliases attn region; Pn is
  // consumed entirely by gemm_kv before attn is first written.
  rmsnorm_rows<<<32768, 256, 0, stream>>>(P, inw, Pn);

  // fused: kproj = Pn @ Wk^T ; vT = per-batch transpose of Pn @ Wv^T
  gemm_kv<<<2048, 512, 0, stream>>>(Pn, Wkh, Wvh, kproj, vT);

  // working slots live in d_out (fp32)
  hipMemcpyAsync(out, slots, 2097152, hipMemcpyDeviceToDevice, stream);

  for (int it = 0; it < 3; ++it) {
    slots_prep<<<512, 256, 0, stream>>>(out, snw, sn, sbf, rowsum);
    // q = sn @ Wq^T
    gemm_bt<64, 64, 32, 32, 1, 0><<<dim3(16, 8, 1), 256, 0, stream>>>(
        sn, Wqh, qb, 1024, 1024, 1024, 1024, 0, 0, 0, 0, 1.0f);
    // scores+softmax+rowsum fused
    attn_fused<<<dim3(32, 8, 1), 256, 0, stream>>>(qb, kproj, attn, rowsum);
    // upd partials: (attn @ v) split 4-way over m
    gemm_bt<64, 64, 32, 32, 0, 1024><<<dim3(16, 4, 8), 256, 0, stream>>>(
        attn, vT, part, 4096, 4096, 1024, 4096, 262144, 4194304, 65536, 524288, 1.0f);
    upd_reduce<<<512, 256, 0, stream>>>(part, rowsum, upd);
    // gx = upd @ wih^T ; gh = slots @ whh^T  (fp32 out)
    gemm_bt<64, 64, 32, 32, 0, 0><<<dim3(48, 8, 1), 256, 0, stream>>>(
        upd, wihh, gxb, 1024, 1024, 3072, 1024, 0, 0, 0, 0, 1.0f);
    gemm_bt<64, 64, 32, 32, 0, 0><<<dim3(48, 8, 1), 256, 0, stream>>>(
        sbf, whhh, ghb, 1024, 1024, 3072, 1024, 0, 0, 0, 0, 1.0f);
    gru_gates<<<2048, 256, 0, stream>>>(gxb, ghb, bih, bhh, out);
  }
}

// Round 6
// 673.857 us; speedup vs baseline: 1.3141x; 1.0228x over previous
//
#include <hip/hip_runtime.h>
#include <stdint.h>

typedef _Float16 f16;
typedef __attribute__((ext_vector_type(4))) _Float16 f16x4;
typedef __attribute__((ext_vector_type(8))) _Float16 f16x8;
typedef __attribute__((ext_vector_type(4))) float f32x4;

#define EPSF 1e-6f

using as1_cvoid = const __attribute__((address_space(1))) void;
using as3_void  = __attribute__((address_space(3))) void;

__device__ __forceinline__ float blockReduceSum256(float v) {
#pragma unroll
  for (int o = 32; o > 0; o >>= 1) v += __shfl_down(v, o);
  __shared__ float red[4];
  int lane = threadIdx.x & 63, wid = threadIdx.x >> 6;
  if (lane == 0) red[wid] = v;
  __syncthreads();
  return red[0] + red[1] + red[2] + red[3];
}

__global__ __launch_bounds__(256) void cvt_f32_f16(const float* __restrict__ src,
                                                   f16* __restrict__ dst, int n) {
  int i = (blockIdx.x * 256 + threadIdx.x) * 4;
  if (i >= n) return;
  float4 v = *(const float4*)(src + i);
  f16x4 o = {(f16)v.x, (f16)v.y, (f16)v.z, (f16)v.w};
  *(f16x4*)(dst + i) = o;
}

// One block per row of 1024; Y = rmsnorm(X)*w in fp16
__global__ __launch_bounds__(256) void rmsnorm_rows(const float* __restrict__ X,
                                                    const float* __restrict__ w,
                                                    f16* __restrict__ Y) {
  const size_t row = blockIdx.x;
  const int t = threadIdx.x;
  float4 v = ((const float4*)(X + row * 1024))[t];
  float tot = blockReduceSum256(v.x * v.x + v.y * v.y + v.z * v.z + v.w * v.w);
  float s = rsqrtf(tot * (1.0f / 1024.0f) + EPSF);
  float4 wv = ((const float4*)w)[t];
  f16x4 o = {(f16)(v.x * s * wv.x), (f16)(v.y * s * wv.y),
             (f16)(v.z * s * wv.z), (f16)(v.w * s * wv.w)};
  *(f16x4*)(Y + row * 1024 + t * 4) = o;
}

// slots -> sn = rmsnorm(slots)*w (f16), sraw = slots (f16); zero rowsum
__global__ __launch_bounds__(256) void slots_prep(const float* __restrict__ S,
                                                  const float* __restrict__ w,
                                                  f16* __restrict__ sn,
                                                  f16* __restrict__ sraw,
                                                  float* __restrict__ rowsum) {
  const size_t row = blockIdx.x;
  const int t = threadIdx.x;
  if (t == 0) rowsum[row] = 0.f;
  float4 v = ((const float4*)(S + row * 1024))[t];
  float tot = blockReduceSum256(v.x * v.x + v.y * v.y + v.z * v.z + v.w * v.w);
  float s = rsqrtf(tot * (1.0f / 1024.0f) + EPSF);
  float4 wv = ((const float4*)w)[t];
  f16x4 a = {(f16)(v.x * s * wv.x), (f16)(v.y * s * wv.y),
             (f16)(v.z * s * wv.z), (f16)(v.w * s * wv.w)};
  f16x4 b = {(f16)v.x, (f16)v.y, (f16)v.z, (f16)v.w};
  *(f16x4*)(sn + row * 1024 + t * 4) = a;
  *(f16x4*)(sraw + row * 1024 + t * 4) = b;
}

// Deep-pipelined K+V projection. C = A(32768x1024) @ Bcat(2048x1024)^T where
// Bcat = concat(Wk, Wv). Tile 256x256, BK=32, 8 waves (2x4), 4 LDS buffers,
// prefetch distance 3, counted vmcnt (8 in steady state; 8/4/0 epilogue),
// ONE barrier per K-step. LDS XOR swizzle on 128B lines (2-way residual),
// applied on BOTH the pre-swizzled global source and the swizzled LDS read.
// n-tiles 0..3 -> kproj rows; n-tiles 4..7 -> vT[b][d][m] transposed store.
__global__ __launch_bounds__(512, 1) void gemm_kv2(
    const f16* __restrict__ Pn, const f16* __restrict__ Wk, const f16* __restrict__ Wv,
    f16* __restrict__ kproj, f16* __restrict__ vT) {
  __shared__ f16 sm[4][2][8192];  // [buf][A/B][256 rows x 32 k] = 4 x 32 KB
  const int tid = threadIdx.x;
  const int wave = tid >> 6, lane = tid & 63;
  const int cr = lane & 15, kseg = lane >> 4;
  const int wm = wave >> 2, wn = wave & 3;
  // grid: 1024 blocks = 8 xcd x (16 m-tiles x 8 n-tiles); same-m-panel blocks
  // land on one XCD for A-panel L2 reuse.
  const int id = blockIdx.x;
  const int xcd = id & 7, slot = id >> 3;
  const int mt = xcd * 16 + (slot >> 3);
  const int nt = slot & 7;
  const int m0 = mt * 256, n0 = nt * 256;
  const f16* Bmat = (n0 < 1024) ? (Wk + (size_t)n0 * 1024)
                                : (Wv + (size_t)(n0 - 1024) * 1024);

  // staging source (pre-swizzled): thread covers LDS bytes [c*8192 + tid*16).
  // line = o>>7, L' = (o>>4)&7; content(line, L') = row 2*line+(L&1), slot L>>1
  // with L = L' ^ (line&7).
  const int line0 = tid >> 3;                 // 0..63 (c adds 64)
  const int L = (tid & 7) ^ (line0 & 7);
  const int rr = (line0 << 1) + (L & 1);      // row 0..127 (c adds 128)
  const int slB = (L >> 1) << 4;              // k-slot byte offset 0..48
  const char* aB = (const char*)(Pn + (size_t)(m0 + rr) * 1024) + slB;
  const char* bB = (const char*)Bmat + (size_t)rr * 2048 + slB;
  const int ldsW = wave * 1024;               // wave-uniform dest byte offset

  // swizzled read offset for MFMA fragments (per-thread constant, bytes):
  // frag(R=base+cr, kseg): byte = (R>>1)*128 + (((kseg<<1)|(R&1)) ^ (R>>1 &7))*16
  const int rdOff = ((cr >> 1) << 7) + (((((kseg << 1) | (cr & 1))) ^ (cr >> 1)) << 4);

  f32x4 acc[8][4];
  f32x4 vzero = {0.f, 0.f, 0.f, 0.f};
#pragma unroll
  for (int i = 0; i < 8; ++i)
#pragma unroll
    for (int j = 0; j < 4; ++j) acc[i][j] = vzero;

  auto STAGE = [&](int tt) {
    const int b = tt & 3;
    const char* a = aB + tt * 64;
    const char* bb = bB + tt * 64;
    char* la = (char*)(&sm[b][0][0]) + ldsW;
    char* lb = (char*)(&sm[b][1][0]) + ldsW;
    __builtin_amdgcn_global_load_lds((as1_cvoid*)a, (as3_void*)la, 16, 0, 0);
    __builtin_amdgcn_global_load_lds((as1_cvoid*)(a + 262144), (as3_void*)(la + 8192), 16, 0, 0);
    __builtin_amdgcn_global_load_lds((as1_cvoid*)bb, (as3_void*)lb, 16, 0, 0);
    __builtin_amdgcn_global_load_lds((as1_cvoid*)(bb + 262144), (as3_void*)(lb + 8192), 16, 0, 0);
  };

  auto COMPUTE = [&](int t) {
    const int b = t & 3;
    const char* A = (const char*)&sm[b][0][0];
    const char* B = (const char*)&sm[b][1][0];
    f16x8 bf[4];
#pragma unroll
    for (int j = 0; j < 4; ++j)
      bf[j] = *(const f16x8*)(B + (wn << 12) + (j << 10) + rdOff);
    __builtin_amdgcn_s_setprio(1);
#pragma unroll
    for (int i = 0; i < 8; ++i) {
      f16x8 af = *(const f16x8*)(A + (wm << 13) + (i << 10) + rdOff);
#pragma unroll
      for (int j = 0; j < 4; ++j)
        acc[i][j] = __builtin_amdgcn_mfma_f32_16x16x32_f16(af, bf[j], acc[i][j], 0, 0, 0);
    }
    __builtin_amdgcn_s_setprio(0);
  };

  STAGE(0); STAGE(1); STAGE(2);
#pragma unroll 4
  for (int t = 0; t < 29; ++t) {
    asm volatile("s_waitcnt vmcnt(8)" ::: "memory");  // retire tile t (4 loads)
    __builtin_amdgcn_s_barrier();                     // tile t visible to all
    __builtin_amdgcn_sched_barrier(0);
    STAGE(t + 3);  // buf (t+3)&3 = (t-1)&3: all reads of it finished pre-barrier
    COMPUTE(t);
  }
  asm volatile("s_waitcnt vmcnt(8)" ::: "memory");
  __builtin_amdgcn_s_barrier();
  __builtin_amdgcn_sched_barrier(0);
  COMPUTE(29);
  asm volatile("s_waitcnt vmcnt(4)" ::: "memory");
  __builtin_amdgcn_s_barrier();
  __builtin_amdgcn_sched_barrier(0);
  COMPUTE(30);
  asm volatile("s_waitcnt vmcnt(0)" ::: "memory");
  __builtin_amdgcn_s_barrier();
  __builtin_amdgcn_sched_barrier(0);
  COMPUTE(31);

  const int cq = kseg * 4;
  if (n0 < 1024) {
#pragma unroll
    for (int i = 0; i < 8; ++i) {
      const int rb = m0 + wm * 128 + i * 16 + cq;
#pragma unroll
      for (int j = 0; j < 4; ++j) {
        const int gn = n0 + wn * 64 + j * 16 + cr;
#pragma unroll
        for (int r = 0; r < 4; ++r)
          kproj[(size_t)(rb + r) * 1024 + gn] = (f16)acc[i][j][r];
      }
    }
  } else {
    const int nvb = n0 - 1024;
#pragma unroll
    for (int i = 0; i < 8; ++i) {
      const int gm = m0 + wm * 128 + i * 16 + cq;
      const int b = gm >> 12, ml = gm & 4095;
#pragma unroll
      for (int j = 0; j < 4; ++j) {
        const int gn = nvb + wn * 64 + j * 16 + cr;
        f16x4 o = {(f16)acc[i][j][0], (f16)acc[i][j][1],
                   (f16)acc[i][j][2], (f16)acc[i][j][3]};
        *(f16x4*)(vT + ((size_t)b * 1024 + gn) * 4096 + ml) = o;
      }
    }
  }
}

// C = alpha * A(MxK) @ B(NxK)^T ; f16 in. STORE: 0 = fp32 out, 1 = f16 out.
// SPLITK>0: blockIdx.y = K-chunk (width SPLITK), m0 = 0, out += y*sY.
template <int BM, int BN, int WM, int WN, int STORE, int SPLITK>
__global__ __launch_bounds__(256) void gemm_bt(
    const f16* __restrict__ A, const f16* __restrict__ B, void* __restrict__ Cout,
    int lda, int ldb, int ldc, int K, long sA, long sB, long sC, long sY, float alpha) {
  constexpr int AM = WM / 16, AN = WN / 16;
  constexpr int NWN = BN / WN;
  constexpr int AI = BM / 64, BI = BN / 64;
  __shared__ f16 Al[BM * 32];
  __shared__ f16 Bl[BN * 32];
  const int tid = threadIdx.x;
  const int wave = tid >> 6, lane = tid & 63;
  const int wm = wave / NWN, wn = wave % NWN;
  const int z = blockIdx.z;
  const f16* Ab = A + (size_t)z * sA;
  const f16* Bb = B + (size_t)z * sB;
  const int m0 = SPLITK ? 0 : blockIdx.y * BM;
  const int n0 = blockIdx.x * BN;
  const int kbase = SPLITK ? blockIdx.y * SPLITK : 0;
  const int cr = lane & 15, kseg = lane >> 4;

  f32x4 acc[AM][AN];
  f32x4 vzero = {0.f, 0.f, 0.f, 0.f};
#pragma unroll
  for (int i = 0; i < AM; ++i)
#pragma unroll
    for (int j = 0; j < AN; ++j) acc[i][j] = vzero;

  const int nK = SPLITK ? (SPLITK >> 5) : (K >> 5);
  for (int kt = 0; kt < nK; ++kt) {
    const int k0 = kbase + (kt << 5);
#pragma unroll
    for (int it = 0; it < AI; ++it) {
      const int chunk = it * 4 + wave;
      const int off = chunk * 1024 + lane * 16;
      const int r = off >> 6, cb = off & 63;
      const char* src = (const char*)(Ab + (size_t)(m0 + r) * lda + k0) + cb;
      __builtin_amdgcn_global_load_lds((as1_cvoid*)src,
                                       (as3_void*)((char*)Al + chunk * 1024), 16, 0, 0);
    }
#pragma unroll
    for (int it = 0; it < BI; ++it) {
      const int chunk = it * 4 + wave;
      const int off = chunk * 1024 + lane * 16;
      const int r = off >> 6, cb = off & 63;
      const char* src = (const char*)(Bb + (size_t)(n0 + r) * ldb + k0) + cb;
      __builtin_amdgcn_global_load_lds((as1_cvoid*)src,
                                       (as3_void*)((char*)Bl + chunk * 1024), 16, 0, 0);
    }
    __syncthreads();
    f16x8 af[AM], bfv[AN];
#pragma unroll
    for (int i = 0; i < AM; ++i)
      af[i] = *(const f16x8*)&Al[(wm * WM + i * 16 + cr) * 32 + kseg * 8];
#pragma unroll
    for (int j = 0; j < AN; ++j)
      bfv[j] = *(const f16x8*)&Bl[(wn * WN + j * 16 + cr) * 32 + kseg * 8];
#pragma unroll
    for (int i = 0; i < AM; ++i)
#pragma unroll
      for (int j = 0; j < AN; ++j)
        acc[i][j] = __builtin_amdgcn_mfma_f32_16x16x32_f16(af[i], bfv[j], acc[i][j], 0, 0, 0);
    __syncthreads();
  }

  const int cq4 = kseg * 4;
  if constexpr (STORE == 0) {
    float* O = (float*)Cout + (size_t)z * sC + (SPLITK ? (size_t)blockIdx.y * sY : 0);
#pragma unroll
    for (int i = 0; i < AM; ++i) {
      const int rb = m0 + wm * WM + i * 16 + cq4;
#pragma unroll
      for (int j = 0; j < AN; ++j) {
        const int gn = n0 + wn * WN + j * 16 + cr;
#pragma unroll
        for (int r = 0; r < 4; ++r) O[(size_t)(rb + r) * ldc + gn] = acc[i][j][r] * alpha;
      }
    }
  } else {
    f16* O = (f16*)Cout + (size_t)z * sC;
#pragma unroll
    for (int i = 0; i < AM; ++i) {
      const int rb = m0 + wm * WM + i * 16 + cq4;
#pragma unroll
      for (int j = 0; j < AN; ++j) {
        const int gn = n0 + wn * WN + j * 16 + cr;
#pragma unroll
        for (int r = 0; r < 4; ++r)
          O[(size_t)(rb + r) * ldc + gn] = (f16)(acc[i][j][r] * alpha);
      }
    }
  }
}

// Fused scores + softmax(over k=64) + rowsum atomics.
// grid (32 m-chunks, 8 b), 256 threads. attn[b][k][m] f16 out.
__global__ __launch_bounds__(256) void attn_fused(
    const f16* __restrict__ qb, const f16* __restrict__ kproj,
    f16* __restrict__ attn, float* __restrict__ rowsum) {
  constexpr float SCALE = 0.03125f;
  __shared__ f16 Ql[64 * 32];
  __shared__ f16 Kl[128 * 32];
  __shared__ float sc[64][132];
  __shared__ f16 at[64][136];  // 272B rows: 16B-aligned for f16x8 epilogue reads
  const int b = blockIdx.y, m0 = blockIdx.x * 128;
  const int tid = threadIdx.x;
  const int wave = tid >> 6, lane = tid & 63;
  const int cr = lane & 15, kseg = lane >> 4;

  f32x4 acc[8];
  f32x4 vzero = {0.f, 0.f, 0.f, 0.f};
#pragma unroll
  for (int j = 0; j < 8; ++j) acc[j] = vzero;

  for (int kt = 0; kt < 32; ++kt) {
    const int k0 = kt << 5;
    {
      const int off = wave * 1024 + lane * 16;
      const int r = off >> 6, cb = off & 63;
      const char* src = (const char*)(qb + (size_t)(b * 64 + r) * 1024 + k0) + cb;
      __builtin_amdgcn_global_load_lds((as1_cvoid*)src,
                                       (as3_void*)((char*)Ql + wave * 1024), 16, 0, 0);
    }
#pragma unroll
    for (int it = 0; it < 2; ++it) {
      const int chunk = it * 4 + wave;
      const int off = chunk * 1024 + lane * 16;
      const int r = off >> 6, cb = off & 63;
      const char* src = (const char*)(kproj + ((size_t)b * 4096 + m0 + r) * 1024 + k0) + cb;
      __builtin_amdgcn_global_load_lds((as1_cvoid*)src,
                                       (as3_void*)((char*)Kl + chunk * 1024), 16, 0, 0);
    }
    __syncthreads();
    f16x8 aq = *(const f16x8*)&Ql[(wave * 16 + cr) * 32 + kseg * 8];
#pragma unroll
    for (int j = 0; j < 8; ++j) {
      f16x8 bk = *(const f16x8*)&Kl[(j * 16 + cr) * 32 + kseg * 8];
      acc[j] = __builtin_amdgcn_mfma_f32_16x16x32_f16(aq, bk, acc[j], 0, 0, 0);
    }
    __syncthreads();
  }
#pragma unroll
  for (int j = 0; j < 8; ++j)
#pragma unroll
    for (int r = 0; r < 4; ++r)
      sc[wave * 16 + kseg * 4 + r][j * 16 + cr] = acc[j][r] * SCALE;
  __syncthreads();

  if (tid < 128) {
    const int m = tid;
    float v[64];
    float mx = -1e30f;
#pragma unroll
    for (int k = 0; k < 64; ++k) {
      v[k] = sc[k][m];
      mx = fmaxf(mx, v[k]);
    }
    float sum = 0.f;
#pragma unroll
    for (int k = 0; k < 64; ++k) {
      v[k] = __expf(v[k] - mx);
      sum += v[k];
    }
    float inv = 1.0f / sum;
#pragma unroll
    for (int k = 0; k < 64; ++k) at[k][m] = (f16)(v[k] * inv);
  }
  __syncthreads();

  const int k = tid >> 2, seg = tid & 3;
  float s = 0.f;
  f16x8 u[4];
#pragma unroll
  for (int c = 0; c < 4; ++c) {
    u[c] = *(const f16x8*)&at[k][seg * 32 + c * 8];
#pragma unroll
    for (int e = 0; e < 8; ++e) s += (float)u[c][e];
  }
  f16* dst = attn + ((size_t)b * 64 + k) * 4096 + m0 + seg * 32;
#pragma unroll
  for (int c = 0; c < 4; ++c) *(f16x8*)(dst + c * 8) = u[c];
  s += __shfl_down(s, 2);
  s += __shfl_down(s, 1);
  if (seg == 0) atomicAdd(&rowsum[b * 64 + k], s);
}

// sum 4 split-k partials, scale by 1/(rowsum+eps), cvt f16
__global__ __launch_bounds__(256) void upd_reduce(const float* __restrict__ part,
                                                  const float* __restrict__ rowsum,
                                                  f16* __restrict__ upd) {
  const int idx = blockIdx.x * 256 + threadIdx.x;
  const int f0 = idx * 4;
  const int row = f0 >> 10;
  float4 s = *(const float4*)(part + f0);
#pragma unroll
  for (int c = 1; c < 4; ++c) {
    float4 p = *(const float4*)(part + c * 524288 + f0);
    s.x += p.x; s.y += p.y; s.z += p.z; s.w += p.w;
  }
  const float scl = 1.0f / (rowsum[row] + EPSF);
  f16x4 o = {(f16)(s.x * scl), (f16)(s.y * scl), (f16)(s.z * scl), (f16)(s.w * scl)};
  *(f16x4*)(upd + f0) = o;
}

// GRU gates, elementwise over (512,1024); h updated in place (d_out)
__global__ __launch_bounds__(256) void gru_gates(const float* __restrict__ gx,
                                                 const float* __restrict__ gh,
                                                 const float* __restrict__ bih,
                                                 const float* __restrict__ bhh,
                                                 float* __restrict__ h) {
  const int idx = blockIdx.x * 256 + threadIdx.x;
  const int row = idx >> 10, col = idx & 1023;
  const float* gxr = gx + (size_t)row * 3072;
  const float* ghr = gh + (size_t)row * 3072;
  float xr = gxr[col] + bih[col];
  float xz = gxr[col + 1024] + bih[col + 1024];
  float xn = gxr[col + 2048] + bih[col + 2048];
  float hr = ghr[col] + bhh[col];
  float hz = ghr[col + 1024] + bhh[col + 1024];
  float hn = ghr[col + 2048] + bhh[col + 2048];
  float r = 1.f / (1.f + __expf(-(xr + hr)));
  float zz = 1.f / (1.f + __expf(-(xz + hz)));
  float n = tanhf(xn + r * hn);
  float hv = h[idx];
  h[idx] = (1.f - zz) * n + zz * hv;
}

extern "C" void kernel_launch(void* const* d_in, const int* in_sizes, int n_in,
                              void* d_out, int out_size, void* d_ws, size_t ws_size,
                              hipStream_t stream) {
  (void)in_sizes; (void)n_in; (void)out_size; (void)ws_size;
  const float* slots = (const float*)d_in[0];
  const float* P = (const float*)d_in[1];
  const float* Wq = (const float*)d_in[2];
  const float* Wk = (const float*)d_in[3];
  const float* Wv = (const float*)d_in[4];
  const float* wih = (const float*)d_in[5];
  const float* whh = (const float*)d_in[6];
  const float* bih = (const float*)d_in[7];
  const float* bhh = (const float*)d_in[8];
  const float* snw = (const float*)d_in[9];
  const float* inw = (const float*)d_in[10];
  float* out = (float*)d_out;
  char* ws = (char*)d_ws;

  // workspace layout (bytes)
  f16* kproj = (f16*)(ws + 0);           // 64 MB
  f16* vT    = (f16*)(ws + 67108864);    // 64 MB
  char* rgn  = ws + 134217728;           // 64 MB region: Pn, then loop scratch (aliased)
  f16* Pn    = (f16*)rgn;                // 32768x1024 f16
  f16* attn  = (f16*)(rgn + 0);          // 8x64x4096 f16 (4 MB) [aliases Pn; Pn dead]
  float* part = (float*)(rgn + 4194304); // 4x8x64x1024 fp32 (8 MB)
  f16* qb    = (f16*)(rgn + 12582912);   // 512x1024 f16
  f16* sn    = (f16*)(rgn + 13631488);
  f16* sbf   = (f16*)(rgn + 14680064);
  f16* upd   = (f16*)(rgn + 15728640);
  float* gxb = (float*)(rgn + 16777216); // 512x3072 fp32 (6 MB)
  float* ghb = (float*)(rgn + 23068672); // 512x3072 fp32 (6 MB)
  char* wr = ws + 201326592;
  f16* Wqh  = (f16*)(wr + 0);
  f16* Wkh  = (f16*)(wr + 2097152);
  f16* Wvh  = (f16*)(wr + 4194304);
  f16* wihh = (f16*)(wr + 6291456);
  f16* whhh = (f16*)(wr + 12582912);
  float* rowsum = (float*)(wr + 18874368); // 512 fp32

  // weights -> f16
  cvt_f32_f16<<<1024, 256, 0, stream>>>(Wq, Wqh, 1048576);
  cvt_f32_f16<<<1024, 256, 0, stream>>>(Wk, Wkh, 1048576);
  cvt_f32_f16<<<1024, 256, 0, stream>>>(Wv, Wvh, 1048576);
  cvt_f32_f16<<<3072, 256, 0, stream>>>(wih, wihh, 3145728);
  cvt_f32_f16<<<3072, 256, 0, stream>>>(whh, whhh, 3145728);

  // Pn = rmsnorm(P) * input_norm_w  -- Pn aliases attn region; Pn is consumed
  // entirely by gemm_kv2 before attn is first written.
  rmsnorm_rows<<<32768, 256, 0, stream>>>(P, inw, Pn);

  // fused deep-pipelined: kproj = Pn @ Wk^T ; vT = per-batch transpose of Pn @ Wv^T
  gemm_kv2<<<1024, 512, 0, stream>>>(Pn, Wkh, Wvh, kproj, vT);

  // working slots live in d_out (fp32)
  hipMemcpyAsync(out, slots, 2097152, hipMemcpyDeviceToDevice, stream);

  for (int it = 0; it < 3; ++it) {
    slots_prep<<<512, 256, 0, stream>>>(out, snw, sn, sbf, rowsum);
    // q = sn @ Wq^T
    gemm_bt<64, 64, 32, 32, 1, 0><<<dim3(16, 8, 1), 256, 0, stream>>>(
        sn, Wqh, qb, 1024, 1024, 1024, 1024, 0, 0, 0, 0, 1.0f);
    // scores+softmax+rowsum fused
    attn_fused<<<dim3(32, 8, 1), 256, 0, stream>>>(qb, kproj, attn, rowsum);
    // upd partials: (attn @ v) split 4-way over m
    gemm_bt<64, 64, 32, 32, 0, 1024><<<dim3(16, 4, 8), 256, 0, stream>>>(
        attn, vT, part, 4096, 4096, 1024, 4096, 262144, 4194304, 65536, 524288, 1.0f);
    upd_reduce<<<512, 256, 0, stream>>>(part, rowsum, upd);
    // gx = upd @ wih^T ; gh = slots @ whh^T  (fp32 out)
    gemm_bt<64, 64, 32, 32, 0, 0><<<dim3(48, 8, 1), 256, 0, stream>>>(
        upd, wihh, gxb, 1024, 1024, 3072, 1024, 0, 0, 0, 0, 1.0f);
    gemm_bt<64, 64, 32, 32, 0, 0><<<dim3(48, 8, 1), 256, 0, stream>>>(
        sbf, whhh, ghb, 1024, 1024, 3072, 1024, 0, 0, 0, 0, 1.0f);
    gru_gates<<<2048, 256, 0, stream>>>(gxb, ghb, bih, bhh, out);
  }
}